// Round 1
// 307.233 us; speedup vs baseline: 1.1267x; 1.1267x over previous
//
#include <hip/hip_runtime.h>

#define NR 16384
#define DC 2048
#define NG 64
#define EPSJ 1e-4f

typedef __attribute__((ext_vector_type(8))) short short8;
typedef __attribute__((ext_vector_type(16))) float f32x16;

// ws float-offsets
#define GRAM_OFF 0         // 64*1024 f32 (zeroed)
#define CSR_OFF  65536     // 32 replicas * 2048 f32 colsums (zeroed)
#define WBF_OFF  131072    // 64*1024 bf16 (as ushort) = 32768 floats worth
#define BIAS_OFF 163840    // 2048 f32
#define XS_OFF   262144    // 1 MiB: xs bf16 buffer (64 MiB)

__device__ __forceinline__ bool perm_is64(const void* p) {
  const int* p32 = (const int*)p;
  return (p32[1] == 0) && (p32[3] == 0) && (p32[5] == 0);
}
__device__ __forceinline__ int perm_at(const void* p, int k, bool is64) {
  if (is64) return (int)((const long long*)p)[k];
  return ((const int*)p)[k];
}
__device__ __forceinline__ unsigned f2bf(float f) {
  unsigned u = __float_as_uint(f);
  return (u + 0x7fffu + ((u >> 16) & 1u)) >> 16;   // RNE
}

// ---------- K1: gather x -> xs (bf16, shuffled). Wave-private, barrier-free.
__global__ __launch_bounds__(256) void k_gather(const float* __restrict__ x,
                                                const void* __restrict__ perm,
                                                unsigned short* __restrict__ xs,
                                                int xstride) {
  __shared__ float rowb[4][2048];
  const int t = threadIdx.x, wave = t >> 6, lane = t & 63;
  const bool is64 = perm_is64(perm);
  int pc[32];
  #pragma unroll
  for (int s = 0; s < 4; ++s)
    #pragma unroll
    for (int e = 0; e < 8; ++e)
      pc[s * 8 + e] = perm_at(perm, s * 512 + lane * 8 + e, is64);
  float* rb = rowb[wave];
  const int wid = blockIdx.x * 4 + wave;
  #pragma unroll
  for (int r = 0; r < 2; ++r) {
    const int n = wid * 2 + r;
    const float4* xr = (const float4*)(x + (size_t)n * DC);
    #pragma unroll
    for (int s = 0; s < 8; ++s)
      ((float4*)rb)[lane + 64 * s] = xr[lane + 64 * s];
    unsigned short* xsr = xs + (size_t)n * xstride;
    #pragma unroll
    for (int s = 0; s < 4; ++s) {
      const int c0 = s * 512 + lane * 8;
      unsigned b[8];
      #pragma unroll
      for (int e = 0; e < 8; ++e) b[e] = f2bf(rb[pc[s * 8 + e]]);
      uint4 o;
      o.x = b[0] | (b[1] << 16); o.y = b[2] | (b[3] << 16);
      o.z = b[4] | (b[5] << 16); o.w = b[6] | (b[7] << 16);
      *(uint4*)(xsr + c0) = o;
    }
  }
}

// ---------- K2: per-group Gram + colsum via MFMA (A-frag == B-frag). No LDS.
__global__ __launch_bounds__(256) void k_gram(const unsigned short* __restrict__ xs,
                                              int xstride, float* __restrict__ ws) {
  const int t = threadIdx.x, wave = t >> 6, lane = t & 63;
  const int g = blockIdx.x;
  const int slice = blockIdx.y * 4 + wave;      // 0..63, 256 rows each
  const int m = lane & 31, hi = lane >> 5;
  const size_t colbase = (size_t)32 * g + m;
  f32x16 acc;
  #pragma unroll
  for (int i = 0; i < 16; ++i) acc[i] = 0.f;
  float csum = 0.f;
  const int n0 = slice * 256;
  for (int s = 0; s < 16; ++s) {
    const int rbase = n0 + 16 * s + hi * 8;
    unsigned v[8];
    #pragma unroll
    for (int j = 0; j < 8; ++j)
      v[j] = xs[(size_t)(rbase + j) * xstride + colbase];
    #pragma unroll
    for (int j = 0; j < 8; ++j) csum += __uint_as_float(v[j] << 16);
    union { short8 s8; unsigned u[4]; } fr;
    #pragma unroll
    for (int j = 0; j < 4; ++j) fr.u[j] = v[2 * j] | (v[2 * j + 1] << 16);
    // A[m][k]=X[rbase'+k][m], B[k][n]=X[rbase'+k][n]: same fragment -> D += X^T X
    acc = __builtin_amdgcn_mfma_f32_32x32x16_bf16(fr.s8, fr.s8, acc, 0, 0, 0);
  }
  csum += __shfl_xor(csum, 32);
  if (hi == 0)
    atomicAdd(&ws[CSR_OFF + (slice & 31) * DC + 32 * g + m], csum);
  #pragma unroll
  for (int reg = 0; reg < 16; ++reg) {
    const int row = (reg & 3) + 8 * (reg >> 2) + 4 * hi;  // C/D layout (m74/m101)
    atomicAdd(&ws[GRAM_OFF + g * 1024 + row * 32 + m], acc[reg]);
  }
}

// 32x32 matmul helper on padded (stride 36) LDS matrices, 256 threads.
__device__ __forceinline__ void mm32(float* C, const float* A, const float* B, int t) {
  const int i = t >> 3, j0 = 4 * (t & 7);
  float c0 = 0.f, c1 = 0.f, c2 = 0.f, c3 = 0.f;
  #pragma unroll
  for (int k = 0; k < 32; ++k) {
    const float a = A[i * 36 + k];
    const float4 b = *(const float4*)(B + k * 36 + j0);
    c0 += a * b.x; c1 += a * b.y; c2 += a * b.z; c3 += a * b.w;
  }
  __syncthreads();
  C[i * 36 + j0 + 0] = c0; C[i * 36 + j0 + 1] = c1;
  C[i * 36 + j0 + 2] = c2; C[i * 36 + j0 + 3] = c3;
  __syncthreads();
}

// ---------- K3: cov -> W = poly5(cov - I) ~ cov^{-1/2}; store W bf16 + bias f32.
__global__ __launch_bounds__(256) void k_solve(float* __restrict__ ws) {
  __shared__ float ME[32 * 36], M2[32 * 36], MT[32 * 36], MW[32 * 36];
  __shared__ float mvec[32];
  const int t = threadIdx.x, g = blockIdx.x;
  if (t < 32) {
    float s = 0.f;
    for (int r = 0; r < 32; ++r) s += ws[CSR_OFF + r * DC + g * 32 + t];
    mvec[t] = s * (1.f / NR);
  }
  __syncthreads();
  #pragma unroll
  for (int e = 0; e < 4; ++e) {
    const int idx = 4 * t + e; const int i = idx >> 5, j = idx & 31;
    float v = ws[GRAM_OFF + g * 1024 + idx] * (1.f / NR) - mvec[i] * mvec[j];
    if (i == j) v += EPSJ - 1.f;   // E = cov - I
    ME[i * 36 + j] = v;
  }
  __syncthreads();
  const float c1 = -0.5f, c2 = 0.375f, c3 = -0.3125f, c4 = 0.2734375f, c5 = -0.24609375f;
  mm32(M2, ME, ME, t);
  #pragma unroll
  for (int e = 0; e < 4; ++e) {
    const int idx = 4 * t + e; const int i = idx >> 5, j = idx & 31;
    MT[i * 36 + j] = (i == j ? c3 : 0.f) + c4 * ME[i * 36 + j] + c5 * M2[i * 36 + j];
  }
  __syncthreads();
  mm32(MW, ME, MT, t);
  mm32(MT, M2, MW, t);
  #pragma unroll
  for (int e = 0; e < 4; ++e) {
    const int idx = 4 * t + e; const int i = idx >> 5, j = idx & 31;
    MW[i * 36 + j] = (i == j ? 1.f : 0.f) + c1 * ME[i * 36 + j] + c2 * M2[i * 36 + j] + MT[i * 36 + j];
  }
  __syncthreads();
  unsigned short* wbf = (unsigned short*)(ws + WBF_OFF);
  #pragma unroll
  for (int e = 0; e < 4; ++e) {
    const int idx = 4 * t + e; const int i = idx >> 5, j = idx & 31;
    wbf[g * 1024 + idx] = (unsigned short)f2bf(MW[i * 36 + j]);
  }
  if (t < 32) {
    float b = 0.f;
    for (int j = 0; j < 32; ++j) b += mvec[j] * MW[j * 36 + t];
    ws[BIAS_OFF + g * 32 + t] = b;
  }
}

// ---------- K4+K5 fused: y = x*W - bias via MFMA, scatter-unshuffle through
// 128 KB LDS ybuf (bf16 at permuted column), coalesced f32 out write.
// 1024 threads = 16 waves; wave w handles groups 4w..4w+3 of one 32-row tile.
__global__ __launch_bounds__(1024) void k_out(const unsigned short* __restrict__ xs,
                                              int xstride,
                                              const unsigned short* __restrict__ wbf,
                                              const float* __restrict__ bias,
                                              const void* __restrict__ perm,
                                              float* __restrict__ out) {
  __shared__ unsigned short ybuf[32][2048];   // 128 KiB (gfx950: <=160 KiB/WG)
  const int t = threadIdx.x, wave = t >> 6, lane = t & 63;
  const int m = lane & 31, hi = lane >> 5;
  const int n0 = blockIdx.x * 32;
  const bool is64 = perm_is64(perm);
  #pragma unroll
  for (int i = 0; i < 4; ++i) {
    const int g = wave * 4 + i;
    const unsigned short* arow = xs + (size_t)(n0 + m) * xstride + 32 * g;
    short8 a0 = *(const short8*)(arow + 8 * hi);        // A[m][k], k=8hi..8hi+7
    short8 a1 = *(const short8*)(arow + 16 + 8 * hi);   // k=16+8hi..
    const unsigned short* wrow = wbf + g * 1024 + m * 32; // W symmetric: B[k][n]=W[n][k]
    short8 b0 = *(const short8*)(wrow + 8 * hi);
    short8 b1 = *(const short8*)(wrow + 16 + 8 * hi);
    f32x16 acc;
    #pragma unroll
    for (int j = 0; j < 16; ++j) acc[j] = 0.f;
    acc = __builtin_amdgcn_mfma_f32_32x32x16_bf16(a0, b0, acc, 0, 0, 0);
    acc = __builtin_amdgcn_mfma_f32_32x32x16_bf16(a1, b1, acc, 0, 0, 0);
    const float bs = bias[32 * g + m];
    const int pp = perm_at(perm, 32 * g + m, is64);     // out col for y col 32g+m
    #pragma unroll
    for (int reg = 0; reg < 16; ++reg) {
      const int row = (reg & 3) + 8 * (reg >> 2) + 4 * hi;  // C/D layout (m74/m101)
      ybuf[row][pp] = (unsigned short)f2bf(acc[reg] - bs);
    }
  }
  __syncthreads();
  // coalesced out write: wave w streams rows 2w, 2w+1
  #pragma unroll
  for (int r = 0; r < 2; ++r) {
    const int row = wave * 2 + r;
    float* orow = out + (size_t)(n0 + row) * DC;
    #pragma unroll
    for (int s = 0; s < 4; ++s) {
      const int c0 = (lane + 64 * s) * 8;
      uint4 u = *(const uint4*)(&ybuf[row][c0]);
      float4 lo, hi4;
      lo.x  = __uint_as_float(u.x << 16); lo.y  = __uint_as_float(u.x & 0xffff0000u);
      lo.z  = __uint_as_float(u.y << 16); lo.w  = __uint_as_float(u.y & 0xffff0000u);
      hi4.x = __uint_as_float(u.z << 16); hi4.y = __uint_as_float(u.z & 0xffff0000u);
      hi4.z = __uint_as_float(u.w << 16); hi4.w = __uint_as_float(u.w & 0xffff0000u);
      *(float4*)(orow + c0) = lo;
      *(float4*)(orow + c0 + 4) = hi4;
    }
  }
}

extern "C" void kernel_launch(void* const* d_in, const int* in_sizes, int n_in,
                              void* d_out, int out_size, void* d_ws, size_t ws_size,
                              hipStream_t stream) {
  const float* x = (const float*)d_in[0];
  const void* perm = d_in[1];
  float* out = (float*)d_out;
  float* ws = (float*)d_ws;

  const size_t need = (size_t)XS_OFF * 4 + (size_t)NR * DC * 2;
  unsigned short* xs; int stride;
  if (ws_size >= need) { xs = (unsigned short*)(ws + XS_OFF); stride = DC; }
  else { xs = (unsigned short*)out; stride = 2 * DC; }  // bf16 rows in each out-row's first half

  hipMemsetAsync(d_ws, 0, (size_t)131072 * 4, stream);  // gram + colsum replicas

  k_gather<<<2048, 256, 0, stream>>>(x, perm, xs, stride);
  k_gram  <<<dim3(NG, 16), 256, 0, stream>>>(xs, stride, ws);
  k_solve <<<NG, 256, 0, stream>>>(ws);
  k_out   <<<512, 1024, 0, stream>>>(xs, stride,
              (const unsigned short*)(ws + WBF_OFF), ws + BIAS_OFF, perm, out);
}

// Round 2
// 292.233 us; speedup vs baseline: 1.1845x; 1.0513x over previous
//
#include <hip/hip_runtime.h>

#define NR 16384
#define DC 2048
#define NG 64
#define EPSJ 1e-4f

typedef __attribute__((ext_vector_type(8))) short short8;
typedef __attribute__((ext_vector_type(16))) float f32x16;

// ws float-offsets
#define GRAM_OFF 0         // 64*1024 f32 (zeroed; fallback path only)
#define CSR_OFF  65536     // 32 replicas * 2048 f32 colsums (fallback path only)
#define WBF_OFF  131072    // 64*1024 bf16 (as ushort)
#define BIAS_OFF 163840    // 2048 f32
#define XS_OFF   262144    // 1 MiB: xs bf16 buffer (64 MiB)

// out-scratch float-offsets (ws-path only; out is dead until k_out runs)
#define GP_FLOATS 1048576  // 64 groups * 16 slices * 1024 = 4 MiB partial grams
// cs partials: 16 slices * 2048 f32 = 128 KiB, at out + GP_FLOATS

__device__ __forceinline__ bool perm_is64(const void* p) {
  const int* p32 = (const int*)p;
  return (p32[1] == 0) && (p32[3] == 0) && (p32[5] == 0);
}
__device__ __forceinline__ int perm_at(const void* p, int k, bool is64) {
  if (is64) return (int)((const long long*)p)[k];
  return ((const int*)p)[k];
}
__device__ __forceinline__ unsigned f2bf(float f) {
  unsigned u = __float_as_uint(f);
  return (u + 0x7fffu + ((u >> 16) & 1u)) >> 16;   // RNE
}

// ---------- K1: gather x -> xs (bf16, shuffled). Wave-private, barrier-free.
__global__ __launch_bounds__(256) void k_gather(const float* __restrict__ x,
                                                const void* __restrict__ perm,
                                                unsigned short* __restrict__ xs,
                                                int xstride) {
  __shared__ float rowb[4][2048];
  const int t = threadIdx.x, wave = t >> 6, lane = t & 63;
  const bool is64 = perm_is64(perm);
  int pc[32];
  #pragma unroll
  for (int s = 0; s < 4; ++s)
    #pragma unroll
    for (int e = 0; e < 8; ++e)
      pc[s * 8 + e] = perm_at(perm, s * 512 + lane * 8 + e, is64);
  float* rb = rowb[wave];
  const int wid = blockIdx.x * 4 + wave;
  #pragma unroll
  for (int r = 0; r < 2; ++r) {
    const int n = wid * 2 + r;
    const float4* xr = (const float4*)(x + (size_t)n * DC);
    #pragma unroll
    for (int s = 0; s < 8; ++s)
      ((float4*)rb)[lane + 64 * s] = xr[lane + 64 * s];
    unsigned short* xsr = xs + (size_t)n * xstride;
    #pragma unroll
    for (int s = 0; s < 4; ++s) {
      const int c0 = s * 512 + lane * 8;
      unsigned b[8];
      #pragma unroll
      for (int e = 0; e < 8; ++e) b[e] = f2bf(rb[pc[s * 8 + e]]);
      uint4 o;
      o.x = b[0] | (b[1] << 16); o.y = b[2] | (b[3] << 16);
      o.z = b[4] | (b[5] << 16); o.w = b[6] | (b[7] << 16);
      *(uint4*)(xsr + c0) = o;
    }
  }
}

// ---------- K2: per-group Gram + colsum via MFMA (A-frag == B-frag). No global atomics
// in the ws-path: 4-wave LDS reduce -> one non-atomic partial per block (16/group).
template<bool WSP>
__global__ __launch_bounds__(256) void k_gram(const unsigned short* __restrict__ xs,
                                              int xstride, float* __restrict__ ws,
                                              float* __restrict__ gp,
                                              float* __restrict__ cs) {
  const int t = threadIdx.x, wave = t >> 6, lane = t & 63;
  const int g = blockIdx.x;
  const int by = blockIdx.y;
  const int slice = by * 4 + wave;              // 0..63, 256 rows each
  const int m = lane & 31, hi = lane >> 5;
  const size_t colbase = (size_t)32 * g + m;
  f32x16 acc;
  #pragma unroll
  for (int i = 0; i < 16; ++i) acc[i] = 0.f;
  float csum = 0.f;
  const int n0 = slice * 256;
  for (int s = 0; s < 16; ++s) {
    const int rbase = n0 + 16 * s + hi * 8;
    unsigned v[8];
    #pragma unroll
    for (int j = 0; j < 8; ++j)
      v[j] = xs[(size_t)(rbase + j) * xstride + colbase];
    #pragma unroll
    for (int j = 0; j < 8; ++j) csum += __uint_as_float(v[j] << 16);
    union { short8 s8; unsigned u[4]; } fr;
    #pragma unroll
    for (int j = 0; j < 4; ++j) fr.u[j] = v[2 * j] | (v[2 * j + 1] << 16);
    // A[m][k]=X[rbase'+k][m], B[k][n]=X[rbase'+k][n]: same fragment -> D += X^T X
    acc = __builtin_amdgcn_mfma_f32_32x32x16_bf16(fr.s8, fr.s8, acc, 0, 0, 0);
  }
  csum += __shfl_xor(csum, 32);
  if constexpr (WSP) {
    __shared__ float red[4][1024];   // 16 KiB
    __shared__ float csr[4][32];
    #pragma unroll
    for (int reg = 0; reg < 16; ++reg) {
      const int row = (reg & 3) + 8 * (reg >> 2) + 4 * hi;  // C/D layout (m74/m101)
      red[wave][row * 32 + m] = acc[reg];   // bank = m: conflict-free (2-way hi alias is free)
    }
    if (hi == 0) csr[wave][m] = csum;
    __syncthreads();
    const int i4 = t * 4;
    float4 o;
    o.x = red[0][i4 + 0] + red[1][i4 + 0] + red[2][i4 + 0] + red[3][i4 + 0];
    o.y = red[0][i4 + 1] + red[1][i4 + 1] + red[2][i4 + 1] + red[3][i4 + 1];
    o.z = red[0][i4 + 2] + red[1][i4 + 2] + red[2][i4 + 2] + red[3][i4 + 2];
    o.w = red[0][i4 + 3] + red[1][i4 + 3] + red[2][i4 + 3] + red[3][i4 + 3];
    *(float4*)&gp[((size_t)g * 16 + by) * 1024 + i4] = o;
    if (t < 32)
      cs[by * DC + g * 32 + t] = csr[0][t] + csr[1][t] + csr[2][t] + csr[3][t];
  } else {
    if (hi == 0)
      atomicAdd(&ws[CSR_OFF + (slice & 31) * DC + 32 * g + m], csum);
    #pragma unroll
    for (int reg = 0; reg < 16; ++reg) {
      const int row = (reg & 3) + 8 * (reg >> 2) + 4 * hi;
      atomicAdd(&ws[GRAM_OFF + g * 1024 + row * 32 + m], acc[reg]);
    }
  }
}

// 32x32 matmul helper on padded (stride 36) LDS matrices, 256 threads.
__device__ __forceinline__ void mm32(float* C, const float* A, const float* B, int t) {
  const int i = t >> 3, j0 = 4 * (t & 7);
  float c0 = 0.f, c1 = 0.f, c2 = 0.f, c3 = 0.f;
  #pragma unroll
  for (int k = 0; k < 32; ++k) {
    const float a = A[i * 36 + k];
    const float4 b = *(const float4*)(B + k * 36 + j0);
    c0 += a * b.x; c1 += a * b.y; c2 += a * b.z; c3 += a * b.w;
  }
  __syncthreads();
  C[i * 36 + j0 + 0] = c0; C[i * 36 + j0 + 1] = c1;
  C[i * 36 + j0 + 2] = c2; C[i * 36 + j0 + 3] = c3;
  __syncthreads();
}

// ---------- K3: cov -> W = poly5(cov - I) ~ cov^{-1/2}; store W bf16 + bias f32.
template<bool WSP>
__global__ __launch_bounds__(256) void k_solve(float* __restrict__ ws,
                                               const float* __restrict__ gp,
                                               const float* __restrict__ cs) {
  __shared__ float ME[32 * 36], M2[32 * 36], MT[32 * 36], MW[32 * 36];
  __shared__ float mvec[32];
  const int t = threadIdx.x, g = blockIdx.x;
  if (t < 32) {
    float s = 0.f;
    if constexpr (WSP) {
      for (int r = 0; r < 16; ++r) s += cs[r * DC + g * 32 + t];
    } else {
      for (int r = 0; r < 32; ++r) s += ws[CSR_OFF + r * DC + g * 32 + t];
    }
    mvec[t] = s * (1.f / NR);
  }
  __syncthreads();
  float gv[4];
  if constexpr (WSP) {
    float4 gs = make_float4(0.f, 0.f, 0.f, 0.f);
    for (int sl = 0; sl < 16; ++sl) {
      float4 p = *(const float4*)&gp[((size_t)g * 16 + sl) * 1024 + 4 * t];
      gs.x += p.x; gs.y += p.y; gs.z += p.z; gs.w += p.w;
    }
    gv[0] = gs.x; gv[1] = gs.y; gv[2] = gs.z; gv[3] = gs.w;
  } else {
    #pragma unroll
    for (int e = 0; e < 4; ++e) gv[e] = ws[GRAM_OFF + g * 1024 + 4 * t + e];
  }
  #pragma unroll
  for (int e = 0; e < 4; ++e) {
    const int idx = 4 * t + e; const int i = idx >> 5, j = idx & 31;
    float v = gv[e] * (1.f / NR) - mvec[i] * mvec[j];
    if (i == j) v += EPSJ - 1.f;   // E = cov - I
    ME[i * 36 + j] = v;
  }
  __syncthreads();
  const float c1 = -0.5f, c2 = 0.375f, c3 = -0.3125f, c4 = 0.2734375f, c5 = -0.24609375f;
  mm32(M2, ME, ME, t);
  #pragma unroll
  for (int e = 0; e < 4; ++e) {
    const int idx = 4 * t + e; const int i = idx >> 5, j = idx & 31;
    MT[i * 36 + j] = (i == j ? c3 : 0.f) + c4 * ME[i * 36 + j] + c5 * M2[i * 36 + j];
  }
  __syncthreads();
  mm32(MW, ME, MT, t);
  mm32(MT, M2, MW, t);
  #pragma unroll
  for (int e = 0; e < 4; ++e) {
    const int idx = 4 * t + e; const int i = idx >> 5, j = idx & 31;
    MW[i * 36 + j] = (i == j ? 1.f : 0.f) + c1 * ME[i * 36 + j] + c2 * M2[i * 36 + j] + MT[i * 36 + j];
  }
  __syncthreads();
  unsigned short* wbf = (unsigned short*)(ws + WBF_OFF);
  #pragma unroll
  for (int e = 0; e < 4; ++e) {
    const int idx = 4 * t + e; const int i = idx >> 5, j = idx & 31;
    wbf[g * 1024 + idx] = (unsigned short)f2bf(MW[i * 36 + j]);
  }
  if (t < 32) {
    float b = 0.f;
    for (int j = 0; j < 32; ++j) b += mvec[j] * MW[j * 36 + t];
    ws[BIAS_OFF + g * 32 + t] = b;
  }
}

// ---------- K4+K5 fused: y = x*W - bias via MFMA, scatter-unshuffle through
// 128 KB LDS ybuf (bf16 at permuted column), coalesced f32 out write.
// 1024 threads = 16 waves; wave w handles groups 4w..4w+3 of one 32-row tile.
__global__ __launch_bounds__(1024) void k_out(const unsigned short* __restrict__ xs,
                                              int xstride,
                                              const unsigned short* __restrict__ wbf,
                                              const float* __restrict__ bias,
                                              const void* __restrict__ perm,
                                              float* __restrict__ out) {
  __shared__ unsigned short ybuf[32][2048];   // 128 KiB (gfx950: <=160 KiB/WG)
  const int t = threadIdx.x, wave = t >> 6, lane = t & 63;
  const int m = lane & 31, hi = lane >> 5;
  const int n0 = blockIdx.x * 32;
  const bool is64 = perm_is64(perm);
  #pragma unroll
  for (int i = 0; i < 4; ++i) {
    const int g = wave * 4 + i;
    const unsigned short* arow = xs + (size_t)(n0 + m) * xstride + 32 * g;
    short8 a0 = *(const short8*)(arow + 8 * hi);        // A[m][k], k=8hi..8hi+7
    short8 a1 = *(const short8*)(arow + 16 + 8 * hi);   // k=16+8hi..
    const unsigned short* wrow = wbf + g * 1024 + m * 32; // W symmetric: B[k][n]=W[n][k]
    short8 b0 = *(const short8*)(wrow + 8 * hi);
    short8 b1 = *(const short8*)(wrow + 16 + 8 * hi);
    f32x16 acc;
    #pragma unroll
    for (int j = 0; j < 16; ++j) acc[j] = 0.f;
    acc = __builtin_amdgcn_mfma_f32_32x32x16_bf16(a0, b0, acc, 0, 0, 0);
    acc = __builtin_amdgcn_mfma_f32_32x32x16_bf16(a1, b1, acc, 0, 0, 0);
    const float bs = bias[32 * g + m];
    const int pp = perm_at(perm, 32 * g + m, is64);     // out col for y col 32g+m
    #pragma unroll
    for (int reg = 0; reg < 16; ++reg) {
      const int row = (reg & 3) + 8 * (reg >> 2) + 4 * hi;  // C/D layout (m74/m101)
      ybuf[row][pp] = (unsigned short)f2bf(acc[reg] - bs);
    }
  }
  __syncthreads();
  // coalesced out write: wave w streams rows 2w, 2w+1
  #pragma unroll
  for (int r = 0; r < 2; ++r) {
    const int row = wave * 2 + r;
    float* orow = out + (size_t)(n0 + row) * DC;
    #pragma unroll
    for (int s = 0; s < 4; ++s) {
      const int c0 = (lane + 64 * s) * 8;
      uint4 u = *(const uint4*)(&ybuf[row][c0]);
      float4 lo, hi4;
      lo.x  = __uint_as_float(u.x << 16); lo.y  = __uint_as_float(u.x & 0xffff0000u);
      lo.z  = __uint_as_float(u.y << 16); lo.w  = __uint_as_float(u.y & 0xffff0000u);
      hi4.x = __uint_as_float(u.z << 16); hi4.y = __uint_as_float(u.z & 0xffff0000u);
      hi4.z = __uint_as_float(u.w << 16); hi4.w = __uint_as_float(u.w & 0xffff0000u);
      *(float4*)(orow + c0) = lo;
      *(float4*)(orow + c0 + 4) = hi4;
    }
  }
}

extern "C" void kernel_launch(void* const* d_in, const int* in_sizes, int n_in,
                              void* d_out, int out_size, void* d_ws, size_t ws_size,
                              hipStream_t stream) {
  const float* x = (const float*)d_in[0];
  const void* perm = d_in[1];
  float* out = (float*)d_out;
  float* ws = (float*)d_ws;

  const size_t need = (size_t)XS_OFF * 4 + (size_t)NR * DC * 2;
  const bool wsp = (ws_size >= need);
  unsigned short* xs; int stride;
  if (wsp) { xs = (unsigned short*)(ws + XS_OFF); stride = DC; }
  else { xs = (unsigned short*)out; stride = 2 * DC; }  // bf16 rows in each out-row's first half

  k_gather<<<2048, 256, 0, stream>>>(x, perm, xs, stride);

  if (wsp) {
    // out is dead scratch until k_out: stage non-atomic gram/colsum partials there.
    float* gp = out;
    float* cs = out + GP_FLOATS;
    k_gram<true> <<<dim3(NG, 16), 256, 0, stream>>>(xs, stride, ws, gp, cs);
    k_solve<true><<<NG, 256, 0, stream>>>(ws, gp, cs);
  } else {
    hipMemsetAsync(d_ws, 0, (size_t)131072 * 4, stream);  // gram + colsum replicas
    k_gram<false> <<<dim3(NG, 16), 256, 0, stream>>>(xs, stride, ws, ws, ws);
    k_solve<false><<<NG, 256, 0, stream>>>(ws, ws, ws);
  }

  k_out<<<512, 1024, 0, stream>>>(xs, stride,
              (const unsigned short*)(ws + WBF_OFF), ws + BIAS_OFF, perm, out);
}

// Round 3
// 286.289 us; speedup vs baseline: 1.2091x; 1.0208x over previous
//
#include <hip/hip_runtime.h>

#define NR 16384
#define DC 2048
#define NG 64
#define EPSJ 1e-4f

typedef __attribute__((ext_vector_type(8))) short short8;
typedef __attribute__((ext_vector_type(16))) float f32x16;

// ws float-offsets
#define GRAM_OFF 0         // 64*1024 f32 (zeroed; fallback path only)
#define CSR_OFF  65536     // 32 replicas * 2048 f32 colsums (fallback path only)
#define WBF_OFF  131072    // 64*1024 bf16 (as ushort)
#define BIAS_OFF 163840    // 2048 f32
#define XS_OFF   262144    // 1 MiB: xs bf16 buffer (64 MiB)

// out-scratch float-offsets (ws-path only; out is dead until k_out runs)
#define GP_FLOATS 1048576  // 64 groups * 16 slices * 1024 = 4 MiB partial grams
// cs partials: 16 slices * 2048 f32 = 128 KiB, at out + GP_FLOATS

// xs layout:
//  WSP  : tiled panels xs[nt][g][r][m], nt=row-tile (32 rows), 32x32 ushort tile
//         offset = ((nt*64+g)<<10) + (r<<5) + m    (ushort units)
//  !WSP : row-major bf16 rows in each out-row's first half (proven fallback)
//         offset = n*4096 + g*32 + m,  n = nt*32+r
__device__ __forceinline__ size_t xs_off(bool wsp, int nt, int g, int r, int m) {
  if (wsp) return ((size_t)(nt * 64 + g) << 10) + (r << 5) + m;
  return (size_t)(nt * 32 + r) * 4096 + g * 32 + m;
}

__device__ __forceinline__ bool perm_is64(const void* p) {
  const int* p32 = (const int*)p;
  return (p32[1] == 0) && (p32[3] == 0) && (p32[5] == 0);
}
__device__ __forceinline__ int perm_at(const void* p, int k, bool is64) {
  if (is64) return (int)((const long long*)p)[k];
  return ((const int*)p)[k];
}
__device__ __forceinline__ unsigned f2bf(float f) {
  unsigned u = __float_as_uint(f);
  return (u + 0x7fffu + ((u >> 16) & 1u)) >> 16;   // RNE
}

// ---------- K1: gather x -> xs (bf16, shuffled). Wave-private, barrier-free.
template<bool WSP>
__global__ __launch_bounds__(256) void k_gather(const float* __restrict__ x,
                                                const void* __restrict__ perm,
                                                unsigned short* __restrict__ xs) {
  __shared__ float rowb[4][2048];
  const int t = threadIdx.x, wave = t >> 6, lane = t & 63;
  const bool is64 = perm_is64(perm);
  int pc[32];
  #pragma unroll
  for (int s = 0; s < 4; ++s)
    #pragma unroll
    for (int e = 0; e < 8; ++e)
      pc[s * 8 + e] = perm_at(perm, s * 512 + lane * 8 + e, is64);
  float* rb = rowb[wave];
  const int wid = blockIdx.x * 4 + wave;
  #pragma unroll
  for (int r = 0; r < 2; ++r) {
    const int n = wid * 2 + r;
    const int nt = n >> 5, rr = n & 31;
    const float4* xr = (const float4*)(x + (size_t)n * DC);
    #pragma unroll
    for (int s = 0; s < 8; ++s)
      ((float4*)rb)[lane + 64 * s] = xr[lane + 64 * s];
    #pragma unroll
    for (int s = 0; s < 4; ++s) {
      unsigned b[8];
      #pragma unroll
      for (int e = 0; e < 8; ++e) b[e] = f2bf(rb[pc[s * 8 + e]]);
      uint4 o;
      o.x = b[0] | (b[1] << 16); o.y = b[2] | (b[3] << 16);
      o.z = b[4] | (b[5] << 16); o.w = b[6] | (b[7] << 16);
      // chunk s covers shuffled cols s*512+lane*8 .. +8: group g = s*16+lane/4,
      // m0 = (lane&3)*8 (all 8 elems in one group)
      const int g = s * 16 + (lane >> 2), m0 = (lane & 3) * 8;
      *(uint4*)(xs + xs_off(WSP, nt, g, rr, m0)) = o;
    }
  }
}

// ---------- K2: per-group Gram + colsum via MFMA (A-frag == B-frag). No global atomics
// in the ws-path: 4-wave LDS reduce -> one non-atomic partial per block (16/group).
template<bool WSP>
__global__ __launch_bounds__(256) void k_gram(const unsigned short* __restrict__ xs,
                                              float* __restrict__ ws,
                                              float* __restrict__ gp,
                                              float* __restrict__ cs) {
  const int t = threadIdx.x, wave = t >> 6, lane = t & 63;
  const int g = blockIdx.x;
  const int by = blockIdx.y;
  const int slice = by * 4 + wave;              // 0..63, 256 rows each
  const int m = lane & 31, hi = lane >> 5;
  f32x16 acc;
  #pragma unroll
  for (int i = 0; i < 16; ++i) acc[i] = 0.f;
  float csum = 0.f;
  const int n0 = slice * 256;
  for (int s = 0; s < 16; ++s) {
    const int rbase = n0 + 16 * s + 8 * hi;     // 8-aligned: stays in one 32-row tile
    const int nt = rbase >> 5, r0 = rbase & 31;
    const unsigned short* tp = xs + xs_off(WSP, nt, g, r0, m);
    const size_t rstride = WSP ? 32 : 4096;
    unsigned v[8];
    #pragma unroll
    for (int j = 0; j < 8; ++j)
      v[j] = tp[(size_t)j * rstride];
    #pragma unroll
    for (int j = 0; j < 8; ++j) csum += __uint_as_float(v[j] << 16);
    union { short8 s8; unsigned u[4]; } fr;
    #pragma unroll
    for (int j = 0; j < 4; ++j) fr.u[j] = v[2 * j] | (v[2 * j + 1] << 16);
    // A[m][k]=X[rbase'+k][m], B[k][n]=X[rbase'+k][n]: same fragment -> D += X^T X
    acc = __builtin_amdgcn_mfma_f32_32x32x16_bf16(fr.s8, fr.s8, acc, 0, 0, 0);
  }
  csum += __shfl_xor(csum, 32);
  if constexpr (WSP) {
    __shared__ float red[4][1024];   // 16 KiB
    __shared__ float csr[4][32];
    #pragma unroll
    for (int reg = 0; reg < 16; ++reg) {
      const int row = (reg & 3) + 8 * (reg >> 2) + 4 * hi;  // C/D layout (m74/m101)
      red[wave][row * 32 + m] = acc[reg];   // bank = m: conflict-free (2-way hi alias is free)
    }
    if (hi == 0) csr[wave][m] = csum;
    __syncthreads();
    const int i4 = t * 4;
    float4 o;
    o.x = red[0][i4 + 0] + red[1][i4 + 0] + red[2][i4 + 0] + red[3][i4 + 0];
    o.y = red[0][i4 + 1] + red[1][i4 + 1] + red[2][i4 + 1] + red[3][i4 + 1];
    o.z = red[0][i4 + 2] + red[1][i4 + 2] + red[2][i4 + 2] + red[3][i4 + 2];
    o.w = red[0][i4 + 3] + red[1][i4 + 3] + red[2][i4 + 3] + red[3][i4 + 3];
    *(float4*)&gp[((size_t)g * 16 + by) * 1024 + i4] = o;
    if (t < 32)
      cs[by * DC + g * 32 + t] = csr[0][t] + csr[1][t] + csr[2][t] + csr[3][t];
  } else {
    if (hi == 0)
      atomicAdd(&ws[CSR_OFF + (slice & 31) * DC + 32 * g + m], csum);
    #pragma unroll
    for (int reg = 0; reg < 16; ++reg) {
      const int row = (reg & 3) + 8 * (reg >> 2) + 4 * hi;
      atomicAdd(&ws[GRAM_OFF + g * 1024 + row * 32 + m], acc[reg]);
    }
  }
}

// 32x32 matmul helper on padded (stride 36) LDS matrices, 256 threads.
__device__ __forceinline__ void mm32(float* C, const float* A, const float* B, int t) {
  const int i = t >> 3, j0 = 4 * (t & 7);
  float c0 = 0.f, c1 = 0.f, c2 = 0.f, c3 = 0.f;
  #pragma unroll
  for (int k = 0; k < 32; ++k) {
    const float a = A[i * 36 + k];
    const float4 b = *(const float4*)(B + k * 36 + j0);
    c0 += a * b.x; c1 += a * b.y; c2 += a * b.z; c3 += a * b.w;
  }
  __syncthreads();
  C[i * 36 + j0 + 0] = c0; C[i * 36 + j0 + 1] = c1;
  C[i * 36 + j0 + 2] = c2; C[i * 36 + j0 + 3] = c3;
  __syncthreads();
}

// ---------- K3: cov -> W = poly5(cov - I) ~ cov^{-1/2}; store W bf16 + bias f32.
template<bool WSP>
__global__ __launch_bounds__(256) void k_solve(float* __restrict__ ws,
                                               const float* __restrict__ gp,
                                               const float* __restrict__ cs) {
  __shared__ float ME[32 * 36], M2[32 * 36], MT[32 * 36], MW[32 * 36];
  __shared__ float mvec[32];
  const int t = threadIdx.x, g = blockIdx.x;
  if (t < 32) {
    float s = 0.f;
    if constexpr (WSP) {
      for (int r = 0; r < 16; ++r) s += cs[r * DC + g * 32 + t];
    } else {
      for (int r = 0; r < 32; ++r) s += ws[CSR_OFF + r * DC + g * 32 + t];
    }
    mvec[t] = s * (1.f / NR);
  }
  __syncthreads();
  float gv[4];
  if constexpr (WSP) {
    float4 gs = make_float4(0.f, 0.f, 0.f, 0.f);
    for (int sl = 0; sl < 16; ++sl) {
      float4 p = *(const float4*)&gp[((size_t)g * 16 + sl) * 1024 + 4 * t];
      gs.x += p.x; gs.y += p.y; gs.z += p.z; gs.w += p.w;
    }
    gv[0] = gs.x; gv[1] = gs.y; gv[2] = gs.z; gv[3] = gs.w;
  } else {
    #pragma unroll
    for (int e = 0; e < 4; ++e) gv[e] = ws[GRAM_OFF + g * 1024 + 4 * t + e];
  }
  #pragma unroll
  for (int e = 0; e < 4; ++e) {
    const int idx = 4 * t + e; const int i = idx >> 5, j = idx & 31;
    float v = gv[e] * (1.f / NR) - mvec[i] * mvec[j];
    if (i == j) v += EPSJ - 1.f;   // E = cov - I
    ME[i * 36 + j] = v;
  }
  __syncthreads();
  const float c1 = -0.5f, c2 = 0.375f, c3 = -0.3125f, c4 = 0.2734375f, c5 = -0.24609375f;
  mm32(M2, ME, ME, t);
  #pragma unroll
  for (int e = 0; e < 4; ++e) {
    const int idx = 4 * t + e; const int i = idx >> 5, j = idx & 31;
    MT[i * 36 + j] = (i == j ? c3 : 0.f) + c4 * ME[i * 36 + j] + c5 * M2[i * 36 + j];
  }
  __syncthreads();
  mm32(MW, ME, MT, t);
  mm32(MT, M2, MW, t);
  #pragma unroll
  for (int e = 0; e < 4; ++e) {
    const int idx = 4 * t + e; const int i = idx >> 5, j = idx & 31;
    MW[i * 36 + j] = (i == j ? 1.f : 0.f) + c1 * ME[i * 36 + j] + c2 * M2[i * 36 + j] + MT[i * 36 + j];
  }
  __syncthreads();
  unsigned short* wbf = (unsigned short*)(ws + WBF_OFF);
  #pragma unroll
  for (int e = 0; e < 4; ++e) {
    const int idx = 4 * t + e; const int i = idx >> 5, j = idx & 31;
    wbf[g * 1024 + idx] = (unsigned short)f2bf(MW[i * 36 + j]);
  }
  if (t < 32) {
    float b = 0.f;
    for (int j = 0; j < 32; ++j) b += mvec[j] * MW[j * 36 + t];
    ws[BIAS_OFF + g * 32 + t] = b;
  }
}

// ---------- K4+K5 fused: y = x*W - bias via MFMA, scatter-unshuffle through
// 128 KB LDS ybuf (bf16 at permuted column), coalesced f32 out write.
// 1024 threads = 16 waves; wave w handles groups 4w..4w+3 of one 32-row tile.
template<bool WSP>
__global__ __launch_bounds__(1024) void k_out(const unsigned short* __restrict__ xs,
                                              const unsigned short* __restrict__ wbf,
                                              const float* __restrict__ bias,
                                              const void* __restrict__ perm,
                                              float* __restrict__ out) {
  __shared__ unsigned short ybuf[32][2048];   // 128 KiB (gfx950: <=160 KiB/WG)
  const int t = threadIdx.x, wave = t >> 6, lane = t & 63;
  const int m = lane & 31, hi = lane >> 5;
  const int nt = blockIdx.x, n0 = nt * 32;
  const bool is64 = perm_is64(perm);
  #pragma unroll
  for (int i = 0; i < 4; ++i) {
    const int g = wave * 4 + i;
    // A[m][k] = xs[nt][g][m][k]; WSP: one contiguous 2KB tile per (nt,g)
    const unsigned short* arow = xs + xs_off(WSP, nt, g, m, 0);
    short8 a0 = *(const short8*)(arow + 8 * hi);        // k=8hi..8hi+7
    short8 a1 = *(const short8*)(arow + 16 + 8 * hi);   // k=16+8hi..
    const unsigned short* wrow = wbf + g * 1024 + m * 32; // W symmetric: B[k][n]=W[n][k]
    short8 b0 = *(const short8*)(wrow + 8 * hi);
    short8 b1 = *(const short8*)(wrow + 16 + 8 * hi);
    f32x16 acc;
    #pragma unroll
    for (int j = 0; j < 16; ++j) acc[j] = 0.f;
    acc = __builtin_amdgcn_mfma_f32_32x32x16_bf16(a0, b0, acc, 0, 0, 0);
    acc = __builtin_amdgcn_mfma_f32_32x32x16_bf16(a1, b1, acc, 0, 0, 0);
    const float bs = bias[32 * g + m];
    const int pp = perm_at(perm, 32 * g + m, is64);     // out col for y col 32g+m
    #pragma unroll
    for (int reg = 0; reg < 16; ++reg) {
      const int row = (reg & 3) + 8 * (reg >> 2) + 4 * hi;  // C/D layout (m74/m101)
      ybuf[row][pp] = (unsigned short)f2bf(acc[reg] - bs);
    }
  }
  __syncthreads();
  // coalesced out write: wave w streams rows 2w, 2w+1
  #pragma unroll
  for (int r = 0; r < 2; ++r) {
    const int row = wave * 2 + r;
    float* orow = out + (size_t)(n0 + row) * DC;
    #pragma unroll
    for (int s = 0; s < 4; ++s) {
      const int c0 = (lane + 64 * s) * 8;
      uint4 u = *(const uint4*)(&ybuf[row][c0]);
      float4 lo, hi4;
      lo.x  = __uint_as_float(u.x << 16); lo.y  = __uint_as_float(u.x & 0xffff0000u);
      lo.z  = __uint_as_float(u.y << 16); lo.w  = __uint_as_float(u.y & 0xffff0000u);
      hi4.x = __uint_as_float(u.z << 16); hi4.y = __uint_as_float(u.z & 0xffff0000u);
      hi4.z = __uint_as_float(u.w << 16); hi4.w = __uint_as_float(u.w & 0xffff0000u);
      *(float4*)(orow + c0) = lo;
      *(float4*)(orow + c0 + 4) = hi4;
    }
  }
}

extern "C" void kernel_launch(void* const* d_in, const int* in_sizes, int n_in,
                              void* d_out, int out_size, void* d_ws, size_t ws_size,
                              hipStream_t stream) {
  const float* x = (const float*)d_in[0];
  const void* perm = d_in[1];
  float* out = (float*)d_out;
  float* ws = (float*)d_ws;

  const size_t need = (size_t)XS_OFF * 4 + (size_t)NR * DC * 2;
  const bool wsp = (ws_size >= need);

  if (wsp) {
    unsigned short* xs = (unsigned short*)(ws + XS_OFF);
    // out is dead scratch until k_out: stage non-atomic gram/colsum partials there.
    float* gp = out;
    float* cs = out + GP_FLOATS;
    k_gather<true><<<2048, 256, 0, stream>>>(x, perm, xs);
    k_gram<true>  <<<dim3(NG, 16), 256, 0, stream>>>(xs, ws, gp, cs);
    k_solve<true> <<<NG, 256, 0, stream>>>(ws, gp, cs);
    k_out<true>   <<<512, 1024, 0, stream>>>(xs,
                     (const unsigned short*)(ws + WBF_OFF), ws + BIAS_OFF, perm, out);
  } else {
    unsigned short* xs = (unsigned short*)out;   // bf16 rows in out-row first halves
    hipMemsetAsync(d_ws, 0, (size_t)131072 * 4, stream);  // gram + colsum replicas
    k_gather<false><<<2048, 256, 0, stream>>>(x, perm, xs);
    k_gram<false>  <<<dim3(NG, 16), 256, 0, stream>>>(xs, ws, ws, ws);
    k_solve<false> <<<NG, 256, 0, stream>>>(ws, ws, ws);
    k_out<false>   <<<512, 1024, 0, stream>>>(xs,
                     (const unsigned short*)(ws + WBF_OFF), ws + BIAS_OFF, perm, out);
  }
}